// Round 4
// baseline (108.195 us; speedup 1.0000x reference)
//
#include <hip/hip_runtime.h>

namespace {

constexpr int L     = 128;
constexpr int NANG  = 120;
constexpr size_t H16_BYTES = (size_t)2 * NANG * L * L * 2;   // 7,864,320

typedef __fp16 f16x2 __attribute__((ext_vector_type(2)));
typedef __fp16 f16x4 __attribute__((ext_vector_type(4)));
typedef float  f32x4 __attribute__((ext_vector_type(4)));

// Prepass: image f32 -> f16 (rtz, identical bits to the f32 path's cvt of B).
__global__ __launch_bounds__(256) void cvt16_kernel(const float* __restrict__ in,
                                                    unsigned* __restrict__ out) {
    const int i = ((int)blockIdx.x * 256 + (int)threadIdx.x) * 4;
    const float4 v = *reinterpret_cast<const float4*>(in + i);
    f16x2 a = __builtin_amdgcn_cvt_pkrtz(v.x, v.y);
    f16x2 b = __builtin_amdgcn_cvt_pkrtz(v.z, v.w);
    uint2 st;
    st.x = *reinterpret_cast<unsigned*>(&a);
    st.y = *reinterpret_cast<unsigned*>(&b);
    *reinterpret_cast<uint2*>(out + i / 2) = st;
}

// Block: 1024 thr = 16 waves, one (8x8-point tile, b) pair; grid 512 = 2 rounds
// of 256 CUs, 1 block/CU (LDS 123 KiB). Wave = (zq: 32 z's, aset: 30 angles).
// K=16 MFMA, ONE angle per MFMA, 12-row window (8x8 span <= 7*sqrt2+1 < 12,
// exact-floor rlo => slots always <= 11 => quad3 A-frag == 0; quad3 re-reads
// quad0's rows: no extra cache lines). B-frag shared across 4 M-tiles.
// Per-CU unique-line traffic: 2 rounds x 120 ang x 48 lines = 11520 (was 30720).
// A-frags pre-shifted into LDS as {W64lo, W64hi, spill, q0}; per-use select is
// ~6 VALU. Cross-aset reduction in retired wtab LDS; coalesced float2 stores.
template <bool F16>
__global__ __launch_bounds__(1024, 4) void bp_kernel(
    const void* __restrict__ imgv,     // f16: [2,120,128,128] half; f32: float
    const float* __restrict__ angles,  // [120] deg
    float* __restrict__ out)           // [2,128,128,128] f32
{
    constexpr unsigned SLICE = F16 ? 32768u : 65536u;
    constexpr unsigned ROWB  = F16 ? 256u  : 512u;
    constexpr int      RSH   = F16 ? 8 : 9;          // row -> byte shift

    __shared__ uint4    wtab[NANG * 64];   // 120 KiB: [a][p]{Wlo,Whi,spill,q0}
    __shared__ float2   acs[NANG];
    __shared__ unsigned arloB[NANG];       // (window first row) << RSH
    __shared__ alignas(16) float nrmtab[64];

    const int tid = threadIdx.x;
    // XCD chunking (512 = 8 x 64) + Morton tile decode; n's low bit = b so both
    // b-blocks of a tile land in the same XCD chunk.
    const int bid = (int)blockIdx.x;
    const int n   = ((bid & 7) << 6) | (bid >> 3);
    const int b   = n & 1;
    const int tt  = n >> 1;                // 0..255 -> 16x16 tiles
    int xt = 0, yt = 0;
#pragma unroll
    for (int i = 0; i < 4; ++i) {
        xt |= ((tt >> (2 * i)) & 1) << i;
        yt |= ((tt >> (2 * i + 1)) & 1) << i;
    }
    const int xb = xt * 8, yb = yt * 8;
    const float cx = (L - 1) * 0.5f;

    // ---- Phase 0: rotation params + 12-row window floor (EXACT, no margin:
    //      fp-monotone corner min => floor(sy) >= rlo; span bound => s1 <= 11) --
    if (tid < NANG) {
        const float phi = -angles[tid] * 0.017453292519943295f;
        float s, c;
        sincosf(phi, &s, &c);
        const float X0 = (float)xb - cx,  X1 = (float)(xb + 7) - cx;
        const float Y0 = (float)yb - cx,  Y1 = (float)(yb + 7) - cx;
        const float a00 = -s * X0 + c * Y0 + cx;
        const float a01 = -s * X0 + c * Y1 + cx;
        const float a10 = -s * X1 + c * Y0 + cx;
        const float a11 = -s * X1 + c * Y1 + cx;
        const float symin = fminf(fminf(a00, a01), fminf(a10, a11));
        acs[tid]   = make_float2(c, s);
        arloB[tid] = (unsigned)min(max((int)floorf(symin), 0), 116) << RSH;
    }
    if (tid < 64) nrmtab[tid] = 0.f;
    __syncthreads();

    // ---- Phase 1: per-(angle,point) pre-shifted A-fragments + norm sums ----
    float wsum = 0.f;
#pragma unroll
    for (int k = 0; k < 8; ++k) {
        const int e = tid + k * 1024;          // e = a*64 + p (p = tid&63 fixed)
        if (e < NANG * 64) {
            const int p = e & 63;
            const int a = e >> 6;
            const float2 cs = acs[a];
            const int rlo = (int)(arloB[a] >> RSH);
            const float X = (float)(xb + (p >> 3)) - cx;
            const float Y = (float)(yb + (p & 7)) - cx;
            const float sx =  cs.x * X + cs.y * Y + cx;
            const float sy = -cs.y * X + cs.x * Y + cx;
            const float x0f = floorf(sx), y0f = floorf(sy);
            const float wx = sx - x0f,    wy = sy - y0f;
            const int x0 = (int)x0f, y0 = (int)y0f;
            const float mx0 = (x0 >= 0  && x0 <  L)     ? 1.f : 0.f;
            const float mx1 = (x0 >= -1 && x0 <= L - 2) ? 1.f : 0.f;
            const float my0 = (y0 >= 0  && y0 <  L)     ? 1.f : 0.f;
            const float my1 = (y0 >= -1 && y0 <= L - 2) ? 1.f : 0.f;
            const float A   = (1.f - wx) * mx0 + wx * mx1;
            float w0f = (1.f - wy) * my0 * A;
            float w1f = wy * my1 * A;
            const int y0c = min(max(y0, 0), L - 1);
            const int y1c = min(max(y0 + 1, 0), L - 1);
            const int s0  = min(max(y0c - rlo, 0), 11);
            const int s1  = min(max(y1c - rlo, 0), 11);
            if (s0 == s1) { w0f += w1f; w1f = 0.f; }   // clamp collision fold
            f16x2 wh = __builtin_amdgcn_cvt_pkrtz(w0f, w1f);
            const unsigned wbits = *reinterpret_cast<unsigned*>(&wh);
            const unsigned t  = (unsigned)s0 & 3u;
            const unsigned q0 = (unsigned)s0 >> 2;        // 0..2
            const unsigned long long W = (unsigned long long)wbits << (t * 16u);
            const unsigned spill = (t == 3u) ? (wbits >> 16) : 0u;
            uint4 ent;
            ent.x = (unsigned)W;
            ent.y = (unsigned)(W >> 32);
            ent.z = spill;                                // goes to quad q0+1
            ent.w = q0;
            wtab[a * 64 + p] = ent;
            wsum += w0f + w1f;
        }
    }
    atomicAdd(&nrmtab[tid & 63], wsum);
    __syncthreads();   // the ONLY barrier before the epilogue

    const int wave  = tid >> 6;
    const int lane  = tid & 63;
    const int quad  = lane >> 4;
    const int lhalf = lane & 15;
    const int zq    = wave & 3;            // 32 z's
    const int aset  = wave >> 2;           // 30 angles
    const char* __restrict__ imgc = (const char*)imgv;

    const unsigned bbase_s = (unsigned)(b * NANG) * SLICE;
    // per-lane constant offset: quad's 4-row subgroup (quad3 dups quad0) + z
    const unsigned voffc = (unsigned)((quad == 3) ? 0 : quad) * 4u * ROWB
                         + (unsigned)(zq * 32 + 2 * lhalf) * (F16 ? 2u : 4u);
    const int a0 = aset * 30;

    f32x4 acc[4][2] = {};   // [Mtile][z parity]

    auto issue = [&](uint4* e, unsigned* r, float2* rf, int i) {
        const int a = a0 + i;
#pragma unroll
        for (int m = 0; m < 4; ++m)            // A-frag entries, imm m*256
            e[m] = wtab[a * 64 + m * 16 + lhalf];
        const unsigned rlB = __builtin_amdgcn_readfirstlane(arloB[a]);
        const char* pa = imgc + (bbase_s + (unsigned)a * SLICE + rlB);
        if constexpr (F16) {
#pragma unroll
            for (int j = 0; j < 4; ++j)        // row sub_j, imm j*256
                r[j] = *(const unsigned*)(pa + (voffc + (unsigned)j * ROWB));
        } else {
#pragma unroll
            for (int j = 0; j < 4; ++j)
                rf[j] = *(const float2*)(pa + (voffc + (unsigned)j * ROWB));
        }
    };
    auto compute = [&](const uint4* e, const unsigned* r, const float2* rf) {
        union { unsigned u[2]; f16x4 v; } B0, B1;
        if constexpr (F16) {
            B0.u[0] = __builtin_amdgcn_perm(r[1], r[0], 0x05040100u);
            B0.u[1] = __builtin_amdgcn_perm(r[3], r[2], 0x05040100u);
            B1.u[0] = __builtin_amdgcn_perm(r[1], r[0], 0x07060302u);
            B1.u[1] = __builtin_amdgcn_perm(r[3], r[2], 0x07060302u);
        } else {
            const f16x2 h0a = __builtin_amdgcn_cvt_pkrtz(rf[0].x, rf[1].x);
            const f16x2 h0b = __builtin_amdgcn_cvt_pkrtz(rf[2].x, rf[3].x);
            const f16x2 h1a = __builtin_amdgcn_cvt_pkrtz(rf[0].y, rf[1].y);
            const f16x2 h1b = __builtin_amdgcn_cvt_pkrtz(rf[2].y, rf[3].y);
            B0.v = f16x4{h0a.x, h0a.y, h0b.x, h0b.y};
            B1.v = f16x4{h1a.x, h1a.y, h1b.x, h1b.y};
        }
#pragma unroll
        for (int m = 0; m < 4; ++m) {
            const int q0 = (int)e[m].w;
            union { unsigned u[2]; f16x4 v; } af;
            af.u[0] = (quad == q0) ? e[m].x : ((quad == q0 + 1) ? e[m].z : 0u);
            af.u[1] = (quad == q0) ? e[m].y : 0u;
            acc[m][0] = __builtin_amdgcn_mfma_f32_16x16x16f16(af.v, B0.v, acc[m][0], 0, 0, 0);
            acc[m][1] = __builtin_amdgcn_mfma_f32_16x16x16f16(af.v, B1.v, acc[m][1], 0, 0, 0);
        }
    };

    // ---- Main loop: 3-buffer pipeline over this wave's 30 angles ----
    uint4    eA[4], eB[4], eC[4];
    unsigned rA[4], rB[4], rC[4];
    float2   fA[4], fB[4], fC[4];

    issue(eA, rA, fA, 0);
    issue(eB, rB, fB, 1);

    for (int i = 0; i < 30; i += 3) {
        if (i + 2 < 30) issue(eC, rC, fC, i + 2);
        compute(eA, rA, fA);
        if (i + 3 < 30) issue(eA, rA, fA, i + 3);
        compute(eB, rB, fB);
        if (i + 4 < 30) issue(eB, rB, fB, i + 4);
        compute(eC, rC, fC);
    }

    // ---- Cross-aset reduction (asets 1..3 -> aset 0) in retired wtab LDS ----
    __syncthreads();                        // everyone done with wtab/arloB
    float4* red = reinterpret_cast<float4*>(wtab);   // 96 KiB of 120 KiB
    if (aset > 0) {
#pragma unroll
        for (int m = 0; m < 4; ++m)
#pragma unroll
            for (int zg = 0; zg < 2; ++zg)
                red[(((aset - 1) * 4 + zq) * 8 + m * 2 + zg) * 64 + lane] =
                    make_float4(acc[m][zg][0], acc[m][zg][1],
                                acc[m][zg][2], acc[m][zg][3]);
    }
    __syncthreads();
    if (aset == 0) {
#pragma unroll
        for (int s = 0; s < 3; ++s)
#pragma unroll
            for (int m = 0; m < 4; ++m)
#pragma unroll
                for (int zg = 0; zg < 2; ++zg) {
                    const float4 o = red[((s * 4 + zq) * 8 + m * 2 + zg) * 64 + lane];
                    acc[m][zg][0] += o.x; acc[m][zg][1] += o.y;
                    acc[m][zg][2] += o.z; acc[m][zg][3] += o.w;
                }
        // ---- Epilogue: p = m*16 + quad*4 + r; z = zq*32 + 2*lhalf + zg ----
        const int zb = zq * 32 + 2 * lhalf;
#pragma unroll
        for (int m = 0; m < 4; ++m) {
            const float4 nrm4 = *(const float4*)&nrmtab[m * 16 + quad * 4];
            const float iv[4] = { 1.f / (nrm4.x + 1e-11f), 1.f / (nrm4.y + 1e-11f),
                                  1.f / (nrm4.z + 1e-11f), 1.f / (nrm4.w + 1e-11f) };
#pragma unroll
            for (int r = 0; r < 4; ++r) {
                const int p = m * 16 + quad * 4 + r;
                const int x = xb + (p >> 3);
                const int y = yb + (p & 7);
                const float2 o = make_float2(acc[m][0][r] * iv[r],
                                             acc[m][1][r] * iv[r]);
                *reinterpret_cast<float2*>(
                    &out[(((size_t)(b * L + x)) * L + y) * L + zb]) = o;
            }
        }
    }
}

} // namespace

extern "C" void kernel_launch(void* const* d_in, const int* in_sizes, int n_in,
                              void* d_out, int out_size, void* d_ws, size_t ws_size,
                              hipStream_t stream) {
    const float* image  = (const float*)d_in[0];
    const float* angles = (const float*)d_in[1];
    float* out = (float*)d_out;
    (void)in_sizes; (void)n_in; (void)out_size;

    dim3 grid(512);   // 16x16 tiles of 8x8 points x 2 b = 2 rounds of 256 CUs
    if (d_ws != nullptr && ws_size >= H16_BYTES) {
        cvt16_kernel<<<dim3(3840), 256, 0, stream>>>(image, (unsigned*)d_ws);
        bp_kernel<true><<<grid, 1024, 0, stream>>>(d_ws, angles, out);
    } else {
        bp_kernel<false><<<grid, 1024, 0, stream>>>(image, angles, out);
    }
}

// Round 5
// 103.866 us; speedup vs baseline: 1.0417x; 1.0417x over previous
//
#include <hip/hip_runtime.h>

namespace {

constexpr int L     = 128;
constexpr int NANG  = 120;
constexpr size_t H16_BYTES = (size_t)2 * NANG * L * L * 2;   // 7,864,320

typedef __fp16 f16x2 __attribute__((ext_vector_type(2)));
typedef __fp16 f16x4 __attribute__((ext_vector_type(4)));
typedef float  f32x4 __attribute__((ext_vector_type(4)));

// Prepass: image f32 -> f16 (rtz, identical bits to the f32 path's cvt of B).
__global__ __launch_bounds__(256) void cvt16_kernel(const float* __restrict__ in,
                                                    unsigned* __restrict__ out) {
    const int i = ((int)blockIdx.x * 256 + (int)threadIdx.x) * 4;
    const float4 v = *reinterpret_cast<const float4*>(in + i);
    f16x2 a = __builtin_amdgcn_cvt_pkrtz(v.x, v.y);
    f16x2 b = __builtin_amdgcn_cvt_pkrtz(v.z, v.w);
    uint2 st;
    st.x = *reinterpret_cast<unsigned*>(&a);
    st.y = *reinterpret_cast<unsigned*>(&b);
    *reinterpret_cast<uint2*>(out + i / 2) = st;
}

// Grid 256 = ONE block per CU (single pass -- R4's fatal flaw was 2 sequential
// rounds). Block: 1024 thr = 16 waves, one 8x8-point tile, BOTH b, all 128 z.
// Wave = (zq: 32-z chunk, b, aset: 60 angles). K=16 MFMA, one angle per MFMA,
// 12-row window (8x8 span <= 7*sqrt2+2 < 12, exact-floor rlo => slots <= 11 =>
// quad3 A-frag == 0; quad3 re-reads quad0's rows: no extra cache lines).
// B-frag shared across the 4 M-tiles => per-CU unique-line traffic
// 120 ang x 12 rows x 4 chunks x 2 b = 11520 (R2 was 30720), in one pass.
// A-frags pre-shifted in LDS as uint4{Wlo,Whi,spill,q0}; per-use select ~6 VALU.
// aset-pair 2-way reduction through retired wtab LDS; coalesced float2 stores.
template <bool F16>
__global__ __launch_bounds__(1024, 4) void bp_kernel(
    const void* __restrict__ imgv,     // f16: [2,120,128,128] half; f32: float
    const float* __restrict__ angles,  // [120] deg
    float* __restrict__ out)           // [2,128,128,128] f32
{
    constexpr unsigned SLICE = F16 ? 32768u : 65536u;
    constexpr unsigned ROWB  = F16 ? 256u  : 512u;
    constexpr int      RSH   = F16 ? 8 : 9;          // row -> byte shift

    __shared__ uint4    wtab[NANG * 64];   // 120 KiB: [a][p]{Wlo,Whi,spill,q0}
    __shared__ float2   acs[NANG];
    __shared__ unsigned arloB[NANG];       // (window first row) << RSH
    __shared__ alignas(16) float nrmtab[64];

    const int tid = threadIdx.x;
    // XCD chunking (256 = 8 x 32) + Morton tile decode (16x16 tiles of 8x8).
    const int bid = (int)blockIdx.x;
    const int n   = ((bid & 7) << 5) | (bid >> 3);
    int xt = 0, yt = 0;
#pragma unroll
    for (int i = 0; i < 4; ++i) {
        xt |= ((n >> (2 * i)) & 1) << i;
        yt |= ((n >> (2 * i + 1)) & 1) << i;
    }
    const int xb = xt * 8, yb = yt * 8;
    const float cx = (L - 1) * 0.5f;

    // ---- Phase 0: rotation params + 12-row window floor (exact, no margin) --
    if (tid < NANG) {
        const float phi = -angles[tid] * 0.017453292519943295f;
        float s, c;
        sincosf(phi, &s, &c);
        const float X0 = (float)xb - cx,  X1 = (float)(xb + 7) - cx;
        const float Y0 = (float)yb - cx,  Y1 = (float)(yb + 7) - cx;
        const float a00 = -s * X0 + c * Y0 + cx;
        const float a01 = -s * X0 + c * Y1 + cx;
        const float a10 = -s * X1 + c * Y0 + cx;
        const float a11 = -s * X1 + c * Y1 + cx;
        const float symin = fminf(fminf(a00, a01), fminf(a10, a11));
        acs[tid]   = make_float2(c, s);
        arloB[tid] = (unsigned)min(max((int)floorf(symin), 0), 116) << RSH;
    }
    if (tid < 64) nrmtab[tid] = 0.f;
    __syncthreads();

    // ---- Phase 1: per-(angle,point) pre-shifted A-fragments + norm sums ----
    float wsum = 0.f;
#pragma unroll
    for (int k = 0; k < 8; ++k) {
        const int e = tid + k * 1024;          // e = a*64 + p (p = tid&63 fixed)
        if (e < NANG * 64) {
            const int p = e & 63;
            const int a = e >> 6;
            const float2 cs = acs[a];
            const int rlo = (int)(arloB[a] >> RSH);
            const float X = (float)(xb + (p >> 3)) - cx;
            const float Y = (float)(yb + (p & 7)) - cx;
            const float sx =  cs.x * X + cs.y * Y + cx;
            const float sy = -cs.y * X + cs.x * Y + cx;
            const float x0f = floorf(sx), y0f = floorf(sy);
            const float wx = sx - x0f,    wy = sy - y0f;
            const int x0 = (int)x0f, y0 = (int)y0f;
            const float mx0 = (x0 >= 0  && x0 <  L)     ? 1.f : 0.f;
            const float mx1 = (x0 >= -1 && x0 <= L - 2) ? 1.f : 0.f;
            const float my0 = (y0 >= 0  && y0 <  L)     ? 1.f : 0.f;
            const float my1 = (y0 >= -1 && y0 <= L - 2) ? 1.f : 0.f;
            const float A   = (1.f - wx) * mx0 + wx * mx1;
            float w0f = (1.f - wy) * my0 * A;
            float w1f = wy * my1 * A;
            const int y0c = min(max(y0, 0), L - 1);
            const int y1c = min(max(y0 + 1, 0), L - 1);
            const int s0  = min(max(y0c - rlo, 0), 11);
            const int s1  = min(max(y1c - rlo, 0), 11);
            if (s0 == s1) { w0f += w1f; w1f = 0.f; }   // clamp collision fold
            f16x2 wh = __builtin_amdgcn_cvt_pkrtz(w0f, w1f);
            const unsigned wbits = *reinterpret_cast<unsigned*>(&wh);
            const unsigned t  = (unsigned)s0 & 3u;
            const unsigned q0 = (unsigned)s0 >> 2;        // 0..2
            const unsigned long long W = (unsigned long long)wbits << (t * 16u);
            const unsigned spill = (t == 3u) ? (wbits >> 16) : 0u;
            uint4 ent;
            ent.x = (unsigned)W;
            ent.y = (unsigned)(W >> 32);
            ent.z = spill;                                // goes to quad q0+1
            ent.w = q0;
            wtab[a * 64 + p] = ent;
            wsum += w0f + w1f;
        }
    }
    atomicAdd(&nrmtab[tid & 63], wsum);
    __syncthreads();

    const int wave  = tid >> 6;
    const int lane  = tid & 63;
    const int quad  = lane >> 4;
    const int lhalf = lane & 15;
    const int zq    = wave & 3;            // 32-z chunk
    const int b     = (wave >> 2) & 1;
    const int aset  = wave >> 3;           // 60 angles each
    const char* __restrict__ imgc = (const char*)imgv;

    const unsigned bbase_s = __builtin_amdgcn_readfirstlane((unsigned)(b * NANG) * SLICE);
    // per-lane constant offset: quad's 4-row subgroup (quad3 dups quad0) + z
    const unsigned voffc = (unsigned)((quad == 3) ? 0 : quad) * 4u * ROWB
                         + (unsigned)(zq * 32 + 2 * lhalf) * (F16 ? 2u : 4u);
    const int a0 = aset * 60;

    f32x4 acc[4][2] = {};   // [Mtile][z parity]

    auto issue = [&](uint4* e, unsigned* r, float2* rf, int i) {
        const int a = a0 + i;
#pragma unroll
        for (int m = 0; m < 4; ++m)            // A-frag entries, imm m*256
            e[m] = wtab[a * 64 + m * 16 + lhalf];
        const unsigned rlB = __builtin_amdgcn_readfirstlane(arloB[a]);
        const char* pa = imgc + (bbase_s + (unsigned)a * SLICE + rlB);
        if constexpr (F16) {
#pragma unroll
            for (int j = 0; j < 4; ++j)        // row sub_j, imm j*256
                r[j] = *(const unsigned*)(pa + (voffc + (unsigned)j * ROWB));
        } else {
#pragma unroll
            for (int j = 0; j < 4; ++j)
                rf[j] = *(const float2*)(pa + (voffc + (unsigned)j * ROWB));
        }
    };
    auto compute = [&](const uint4* e, const unsigned* r, const float2* rf) {
        union { unsigned u[2]; f16x4 v; } B0, B1;
        if constexpr (F16) {
            B0.u[0] = __builtin_amdgcn_perm(r[1], r[0], 0x05040100u);
            B0.u[1] = __builtin_amdgcn_perm(r[3], r[2], 0x05040100u);
            B1.u[0] = __builtin_amdgcn_perm(r[1], r[0], 0x07060302u);
            B1.u[1] = __builtin_amdgcn_perm(r[3], r[2], 0x07060302u);
        } else {
            const f16x2 h0a = __builtin_amdgcn_cvt_pkrtz(rf[0].x, rf[1].x);
            const f16x2 h0b = __builtin_amdgcn_cvt_pkrtz(rf[2].x, rf[3].x);
            const f16x2 h1a = __builtin_amdgcn_cvt_pkrtz(rf[0].y, rf[1].y);
            const f16x2 h1b = __builtin_amdgcn_cvt_pkrtz(rf[2].y, rf[3].y);
            B0.v = f16x4{h0a.x, h0a.y, h0b.x, h0b.y};
            B1.v = f16x4{h1a.x, h1a.y, h1b.x, h1b.y};
        }
#pragma unroll
        for (int m = 0; m < 4; ++m) {
            const int q0 = (int)e[m].w;
            union { unsigned u[2]; f16x4 v; } af;
            af.u[0] = (quad == q0) ? e[m].x : ((quad == q0 + 1) ? e[m].z : 0u);
            af.u[1] = (quad == q0) ? e[m].y : 0u;
            acc[m][0] = __builtin_amdgcn_mfma_f32_16x16x16f16(af.v, B0.v, acc[m][0], 0, 0, 0);
            acc[m][1] = __builtin_amdgcn_mfma_f32_16x16x16f16(af.v, B1.v, acc[m][1], 0, 0, 0);
        }
    };

    // ---- Main loop: 3-buffer pipeline over this wave's 60 angles ----
    uint4    eA[4], eB[4], eC[4];
    unsigned rA[4], rB[4], rC[4];
    float2   fA[4], fB[4], fC[4];

    issue(eA, rA, fA, 0);
    issue(eB, rB, fB, 1);

    for (int i = 0; i < 60; i += 3) {
        if (i + 2 < 60) issue(eC, rC, fC, i + 2);
        compute(eA, rA, fA);
        if (i + 3 < 60) issue(eA, rA, fA, i + 3);
        compute(eB, rB, fB);
        if (i + 4 < 60) issue(eB, rB, fB, i + 4);
        compute(eC, rC, fC);
    }

    // ---- aset-pair reduction (aset1 -> aset0) in retired wtab LDS ----
    __syncthreads();                        // everyone done with wtab/arloB
    float4* red = reinterpret_cast<float4*>(wtab);   // 64 KiB of 120 KiB
    const int pr = wave & 7;                // pair id: (zq, b)
    if (aset == 1) {
#pragma unroll
        for (int m = 0; m < 4; ++m)
#pragma unroll
            for (int zg = 0; zg < 2; ++zg)
                red[(pr * 8 + m * 2 + zg) * 64 + lane] =
                    make_float4(acc[m][zg][0], acc[m][zg][1],
                                acc[m][zg][2], acc[m][zg][3]);
    }
    __syncthreads();
    if (aset == 0) {
#pragma unroll
        for (int m = 0; m < 4; ++m)
#pragma unroll
            for (int zg = 0; zg < 2; ++zg) {
                const float4 o = red[(pr * 8 + m * 2 + zg) * 64 + lane];
                acc[m][zg][0] += o.x; acc[m][zg][1] += o.y;
                acc[m][zg][2] += o.z; acc[m][zg][3] += o.w;
            }
        // ---- Epilogue: p = m*16 + quad*4 + r; z = zq*32 + 2*lhalf + zg ----
        const int zb = zq * 32 + 2 * lhalf;
#pragma unroll
        for (int m = 0; m < 4; ++m) {
            const float4 nrm4 = *(const float4*)&nrmtab[m * 16 + quad * 4];
            const float iv[4] = { 1.f / (nrm4.x + 1e-11f), 1.f / (nrm4.y + 1e-11f),
                                  1.f / (nrm4.z + 1e-11f), 1.f / (nrm4.w + 1e-11f) };
#pragma unroll
            for (int r = 0; r < 4; ++r) {
                const int p = m * 16 + quad * 4 + r;
                const int x = xb + (p >> 3);
                const int y = yb + (p & 7);
                const float2 o = make_float2(acc[m][0][r] * iv[r],
                                             acc[m][1][r] * iv[r]);
                *reinterpret_cast<float2*>(
                    &out[(((size_t)(b * L + x)) * L + y) * L + zb]) = o;
            }
        }
    }
}

} // namespace

extern "C" void kernel_launch(void* const* d_in, const int* in_sizes, int n_in,
                              void* d_out, int out_size, void* d_ws, size_t ws_size,
                              hipStream_t stream) {
    const float* image  = (const float*)d_in[0];
    const float* angles = (const float*)d_in[1];
    float* out = (float*)d_out;
    (void)in_sizes; (void)n_in; (void)out_size;

    dim3 grid(256);   // 16x16 tiles of 8x8 points, both b per block = 1 per CU
    if (d_ws != nullptr && ws_size >= H16_BYTES) {
        cvt16_kernel<<<dim3(3840), 256, 0, stream>>>(image, (unsigned*)d_ws);
        bp_kernel<true><<<grid, 1024, 0, stream>>>(d_ws, angles, out);
    } else {
        bp_kernel<false><<<grid, 1024, 0, stream>>>(image, angles, out);
    }
}

// Round 6
// 103.769 us; speedup vs baseline: 1.0426x; 1.0009x over previous
//
#include <hip/hip_runtime.h>

namespace {

constexpr int L     = 128;
constexpr int NANG  = 120;
constexpr size_t H16_BYTES = (size_t)2 * NANG * L * L * 2;   // 7,864,320

typedef __fp16 f16x2 __attribute__((ext_vector_type(2)));
typedef __fp16 f16x4 __attribute__((ext_vector_type(4)));
typedef float  f32x4 __attribute__((ext_vector_type(4)));

// Prepass: image f32 -> f16 (rtz, identical bits to the f32 path's cvt of B).
__global__ __launch_bounds__(256) void cvt16_kernel(const float* __restrict__ in,
                                                    unsigned* __restrict__ out) {
    const int i = ((int)blockIdx.x * 256 + (int)threadIdx.x) * 4;
    const float4 v = *reinterpret_cast<const float4*>(in + i);
    f16x2 a = __builtin_amdgcn_cvt_pkrtz(v.x, v.y);
    f16x2 b = __builtin_amdgcn_cvt_pkrtz(v.z, v.w);
    uint2 st;
    st.x = *reinterpret_cast<unsigned*>(&a);
    st.y = *reinterpret_cast<unsigned*>(&b);
    *reinterpret_cast<uint2*>(out + i / 2) = st;
}

// Grid 256 = ONE block per CU, single pass. Block: 1024 thr = 16 waves, one
// 8x8-point tile, BOTH b, all 128 z. Wave = (zq: 32-z chunk, b, aset).
// R6 change vs R5 (L2-reuse pacing -- everything else identical):
//  * aset INTERLEAVE: aset0 = even angles, aset1 = odd (was disjoint halves).
//    All waves/blocks of an XCD touch adjacent angles at any instant ->
//    instantaneous L2 footprint ~64 KB instead of drifting toward ~4 MiB.
//  * raw s_barrier once per 3-angle pipeline group: bounds intra-block wave
//    drift (register-only pipeline state; uniform trip count -> safe), so each
//    image line fetched into L2 is consumed by all ~8-10 sharing blocks while
//    hot, instead of re-fetching from L3 per consumer (R1 showed ~10x
//    L2-miss amplification: 148 MB fetch for a 15.7 MB input).
// K=16 MFMA, one angle per MFMA, 12-row window (8x8 span <= 7*sqrt2+2 < 12,
// exact-floor rlo => slots <= 11 => quad3 A-frag == 0; quad3 re-reads quad0's
// rows: no extra cache lines). B-frag shared across the 4 M-tiles.
// A-frags pre-shifted in LDS as uint4{Wlo,Whi,spill,q0}; per-use select ~6 VALU.
// aset-pair 2-way reduction through retired wtab LDS; coalesced float2 stores.
template <bool F16>
__global__ __launch_bounds__(1024, 4) void bp_kernel(
    const void* __restrict__ imgv,     // f16: [2,120,128,128] half; f32: float
    const float* __restrict__ angles,  // [120] deg
    float* __restrict__ out)           // [2,128,128,128] f32
{
    constexpr unsigned SLICE = F16 ? 32768u : 65536u;
    constexpr unsigned ROWB  = F16 ? 256u  : 512u;
    constexpr int      RSH   = F16 ? 8 : 9;          // row -> byte shift

    __shared__ uint4    wtab[NANG * 64];   // 120 KiB: [a][p]{Wlo,Whi,spill,q0}
    __shared__ float2   acs[NANG];
    __shared__ unsigned arloB[NANG];       // (window first row) << RSH
    __shared__ alignas(16) float nrmtab[64];

    const int tid = threadIdx.x;
    // XCD chunking (256 = 8 x 32) + Morton tile decode (16x16 tiles of 8x8).
    const int bid = (int)blockIdx.x;
    const int n   = ((bid & 7) << 5) | (bid >> 3);
    int xt = 0, yt = 0;
#pragma unroll
    for (int i = 0; i < 4; ++i) {
        xt |= ((n >> (2 * i)) & 1) << i;
        yt |= ((n >> (2 * i + 1)) & 1) << i;
    }
    const int xb = xt * 8, yb = yt * 8;
    const float cx = (L - 1) * 0.5f;

    // ---- Phase 0: rotation params + 12-row window floor (exact, no margin) --
    if (tid < NANG) {
        const float phi = -angles[tid] * 0.017453292519943295f;
        float s, c;
        sincosf(phi, &s, &c);
        const float X0 = (float)xb - cx,  X1 = (float)(xb + 7) - cx;
        const float Y0 = (float)yb - cx,  Y1 = (float)(yb + 7) - cx;
        const float a00 = -s * X0 + c * Y0 + cx;
        const float a01 = -s * X0 + c * Y1 + cx;
        const float a10 = -s * X1 + c * Y0 + cx;
        const float a11 = -s * X1 + c * Y1 + cx;
        const float symin = fminf(fminf(a00, a01), fminf(a10, a11));
        acs[tid]   = make_float2(c, s);
        arloB[tid] = (unsigned)min(max((int)floorf(symin), 0), 116) << RSH;
    }
    if (tid < 64) nrmtab[tid] = 0.f;
    __syncthreads();

    // ---- Phase 1: per-(angle,point) pre-shifted A-fragments + norm sums ----
    float wsum = 0.f;
#pragma unroll
    for (int k = 0; k < 8; ++k) {
        const int e = tid + k * 1024;          // e = a*64 + p (p = tid&63 fixed)
        if (e < NANG * 64) {
            const int p = e & 63;
            const int a = e >> 6;
            const float2 cs = acs[a];
            const int rlo = (int)(arloB[a] >> RSH);
            const float X = (float)(xb + (p >> 3)) - cx;
            const float Y = (float)(yb + (p & 7)) - cx;
            const float sx =  cs.x * X + cs.y * Y + cx;
            const float sy = -cs.y * X + cs.x * Y + cx;
            const float x0f = floorf(sx), y0f = floorf(sy);
            const float wx = sx - x0f,    wy = sy - y0f;
            const int x0 = (int)x0f, y0 = (int)y0f;
            const float mx0 = (x0 >= 0  && x0 <  L)     ? 1.f : 0.f;
            const float mx1 = (x0 >= -1 && x0 <= L - 2) ? 1.f : 0.f;
            const float my0 = (y0 >= 0  && y0 <  L)     ? 1.f : 0.f;
            const float my1 = (y0 >= -1 && y0 <= L - 2) ? 1.f : 0.f;
            const float A   = (1.f - wx) * mx0 + wx * mx1;
            float w0f = (1.f - wy) * my0 * A;
            float w1f = wy * my1 * A;
            const int y0c = min(max(y0, 0), L - 1);
            const int y1c = min(max(y0 + 1, 0), L - 1);
            const int s0  = min(max(y0c - rlo, 0), 11);
            const int s1  = min(max(y1c - rlo, 0), 11);
            if (s0 == s1) { w0f += w1f; w1f = 0.f; }   // clamp collision fold
            f16x2 wh = __builtin_amdgcn_cvt_pkrtz(w0f, w1f);
            const unsigned wbits = *reinterpret_cast<unsigned*>(&wh);
            const unsigned t  = (unsigned)s0 & 3u;
            const unsigned q0 = (unsigned)s0 >> 2;        // 0..2
            const unsigned long long W = (unsigned long long)wbits << (t * 16u);
            const unsigned spill = (t == 3u) ? (wbits >> 16) : 0u;
            uint4 ent;
            ent.x = (unsigned)W;
            ent.y = (unsigned)(W >> 32);
            ent.z = spill;                                // goes to quad q0+1
            ent.w = q0;
            wtab[a * 64 + p] = ent;
            wsum += w0f + w1f;
        }
    }
    atomicAdd(&nrmtab[tid & 63], wsum);
    __syncthreads();

    const int wave  = tid >> 6;
    const int lane  = tid & 63;
    const int quad  = lane >> 4;
    const int lhalf = lane & 15;
    const int zq    = wave & 3;            // 32-z chunk
    const int b     = (wave >> 2) & 1;
    const int aset  = wave >> 3;           // angle parity (interleaved)
    const char* __restrict__ imgc = (const char*)imgv;

    const unsigned bbase_s = __builtin_amdgcn_readfirstlane((unsigned)(b * NANG) * SLICE);
    // per-lane constant offset: quad's 4-row subgroup (quad3 dups quad0) + z
    const unsigned voffc = (unsigned)((quad == 3) ? 0 : quad) * 4u * ROWB
                         + (unsigned)(zq * 32 + 2 * lhalf) * (F16 ? 2u : 4u);

    f32x4 acc[4][2] = {};   // [Mtile][z parity]

    auto issue = [&](uint4* e, unsigned* r, float2* rf, int i) {
        const int a = aset + 2 * i;            // INTERLEAVED angle walk
#pragma unroll
        for (int m = 0; m < 4; ++m)            // A-frag entries, imm m*256
            e[m] = wtab[a * 64 + m * 16 + lhalf];
        const unsigned rlB = __builtin_amdgcn_readfirstlane(arloB[a]);
        const char* pa = imgc + (bbase_s + (unsigned)a * SLICE + rlB);
        if constexpr (F16) {
#pragma unroll
            for (int j = 0; j < 4; ++j)        // row sub_j, imm j*256
                r[j] = *(const unsigned*)(pa + (voffc + (unsigned)j * ROWB));
        } else {
#pragma unroll
            for (int j = 0; j < 4; ++j)
                rf[j] = *(const float2*)(pa + (voffc + (unsigned)j * ROWB));
        }
    };
    auto compute = [&](const uint4* e, const unsigned* r, const float2* rf) {
        union { unsigned u[2]; f16x4 v; } B0, B1;
        if constexpr (F16) {
            B0.u[0] = __builtin_amdgcn_perm(r[1], r[0], 0x05040100u);
            B0.u[1] = __builtin_amdgcn_perm(r[3], r[2], 0x05040100u);
            B1.u[0] = __builtin_amdgcn_perm(r[1], r[0], 0x07060302u);
            B1.u[1] = __builtin_amdgcn_perm(r[3], r[2], 0x07060302u);
        } else {
            const f16x2 h0a = __builtin_amdgcn_cvt_pkrtz(rf[0].x, rf[1].x);
            const f16x2 h0b = __builtin_amdgcn_cvt_pkrtz(rf[2].x, rf[3].x);
            const f16x2 h1a = __builtin_amdgcn_cvt_pkrtz(rf[0].y, rf[1].y);
            const f16x2 h1b = __builtin_amdgcn_cvt_pkrtz(rf[2].y, rf[3].y);
            B0.v = f16x4{h0a.x, h0a.y, h0b.x, h0b.y};
            B1.v = f16x4{h1a.x, h1a.y, h1b.x, h1b.y};
        }
#pragma unroll
        for (int m = 0; m < 4; ++m) {
            const int q0 = (int)e[m].w;
            union { unsigned u[2]; f16x4 v; } af;
            af.u[0] = (quad == q0) ? e[m].x : ((quad == q0 + 1) ? e[m].z : 0u);
            af.u[1] = (quad == q0) ? e[m].y : 0u;
            acc[m][0] = __builtin_amdgcn_mfma_f32_16x16x16f16(af.v, B0.v, acc[m][0], 0, 0, 0);
            acc[m][1] = __builtin_amdgcn_mfma_f32_16x16x16f16(af.v, B1.v, acc[m][1], 0, 0, 0);
        }
    };

    // ---- Main loop: 3-buffer pipeline over this wave's 60 angles,
    //      barrier-paced per group (bounds drift; register-only state,
    //      uniform trip count -> raw s_barrier is safe) ----
    uint4    eA[4], eB[4], eC[4];
    unsigned rA[4], rB[4], rC[4];
    float2   fA[4], fB[4], fC[4];

    issue(eA, rA, fA, 0);
    issue(eB, rB, fB, 1);

    for (int i = 0; i < 60; i += 3) {
        if (i + 2 < 60) issue(eC, rC, fC, i + 2);
        compute(eA, rA, fA);
        if (i + 3 < 60) issue(eA, rA, fA, i + 3);
        compute(eB, rB, fB);
        if (i + 4 < 60) issue(eB, rB, fB, i + 4);
        compute(eC, rC, fC);
        __builtin_amdgcn_s_barrier();          // pacing only
    }

    // ---- aset-pair reduction (aset1 -> aset0) in retired wtab LDS ----
    __syncthreads();                        // everyone done with wtab/arloB
    float4* red = reinterpret_cast<float4*>(wtab);   // 64 KiB of 120 KiB
    const int pr = wave & 7;                // pair id: (zq, b)
    if (aset == 1) {
#pragma unroll
        for (int m = 0; m < 4; ++m)
#pragma unroll
            for (int zg = 0; zg < 2; ++zg)
                red[(pr * 8 + m * 2 + zg) * 64 + lane] =
                    make_float4(acc[m][zg][0], acc[m][zg][1],
                                acc[m][zg][2], acc[m][zg][3]);
    }
    __syncthreads();
    if (aset == 0) {
#pragma unroll
        for (int m = 0; m < 4; ++m)
#pragma unroll
            for (int zg = 0; zg < 2; ++zg) {
                const float4 o = red[(pr * 8 + m * 2 + zg) * 64 + lane];
                acc[m][zg][0] += o.x; acc[m][zg][1] += o.y;
                acc[m][zg][2] += o.z; acc[m][zg][3] += o.w;
            }
        // ---- Epilogue: p = m*16 + quad*4 + r; z = zq*32 + 2*lhalf + zg ----
        const int zb = zq * 32 + 2 * lhalf;
#pragma unroll
        for (int m = 0; m < 4; ++m) {
            const float4 nrm4 = *(const float4*)&nrmtab[m * 16 + quad * 4];
            const float iv[4] = { 1.f / (nrm4.x + 1e-11f), 1.f / (nrm4.y + 1e-11f),
                                  1.f / (nrm4.z + 1e-11f), 1.f / (nrm4.w + 1e-11f) };
#pragma unroll
            for (int r = 0; r < 4; ++r) {
                const int p = m * 16 + quad * 4 + r;
                const int x = xb + (p >> 3);
                const int y = yb + (p & 7);
                const float2 o = make_float2(acc[m][0][r] * iv[r],
                                             acc[m][1][r] * iv[r]);
                *reinterpret_cast<float2*>(
                    &out[(((size_t)(b * L + x)) * L + y) * L + zb]) = o;
            }
        }
    }
}

} // namespace

extern "C" void kernel_launch(void* const* d_in, const int* in_sizes, int n_in,
                              void* d_out, int out_size, void* d_ws, size_t ws_size,
                              hipStream_t stream) {
    const float* image  = (const float*)d_in[0];
    const float* angles = (const float*)d_in[1];
    float* out = (float*)d_out;
    (void)in_sizes; (void)n_in; (void)out_size;

    dim3 grid(256);   // 16x16 tiles of 8x8 points, both b per block = 1 per CU
    if (d_ws != nullptr && ws_size >= H16_BYTES) {
        cvt16_kernel<<<dim3(3840), 256, 0, stream>>>(image, (unsigned*)d_ws);
        bp_kernel<true><<<grid, 1024, 0, stream>>>(d_ws, angles, out);
    } else {
        bp_kernel<false><<<grid, 1024, 0, stream>>>(image, angles, out);
    }
}